// Round 1
// baseline (184.719 us; speedup 1.0000x reference)
//
#include <hip/hip_runtime.h>

#define HIDDEN 1024
#define SEQ 2048
#define NB 2

typedef _Float16 half8 __attribute__((ext_vector_type(8)));
typedef _Float16 half4 __attribute__((ext_vector_type(4)));
typedef float f32x4 __attribute__((ext_vector_type(4)));

// ---------------- cast x fp32 -> fp16 ----------------
__global__ __launch_bounds__(256) void cast_x(const float* __restrict__ x,
                                              _Float16* __restrict__ xh, int n) {
    int i = (blockIdx.x * 256 + threadIdx.x) * 4;
    if (i < n) {
        float4 v = *(const float4*)(x + i);
        half4 h;
        h[0] = (_Float16)v.x; h[1] = (_Float16)v.y;
        h[2] = (_Float16)v.z; h[3] = (_Float16)v.w;
        *(half4*)(xh + i) = h;
    }
}

// ---------------- cast + transpose Wq: wt[n][k] = Wq[k][n] ----------------
__global__ __launch_bounds__(256) void cast_wt(const float* __restrict__ w,
                                               _Float16* __restrict__ wt) {
    __shared__ float tile[32][33];
    int bx = blockIdx.x * 32, by = blockIdx.y * 32;
    int tx = threadIdx.x, ty = threadIdx.y;   // (32, 8)
    #pragma unroll
    for (int i = 0; i < 32; i += 8)
        tile[ty + i][tx] = w[(by + ty + i) * HIDDEN + bx + tx];
    __syncthreads();
    #pragma unroll
    for (int i = 0; i < 32; i += 8)
        wt[(bx + ty + i) * HIDDEN + by + tx] = (_Float16)tile[tx][ty + i];
}

// ---------------- projection GEMM: Q = x @ Wq + bq  (fp16 in/out, fp32 acc) ----------------
// A = xh [4096][1024] row-major; B given as wt [n][k] so B-frag reads are contiguous.
__global__ __launch_bounds__(256) void proj_gemm(const _Float16* __restrict__ A,
                                                 const _Float16* __restrict__ Bt,
                                                 const float* __restrict__ bias,
                                                 _Float16* __restrict__ Q) {
    __shared__ _Float16 As[128][72];  // 64 k-halves + 8 pad
    __shared__ _Float16 Bs[128][72];
    const int m0 = blockIdx.x * 128;
    const int n0 = blockIdx.y * 128;
    const int tid = threadIdx.x;
    const int w = tid >> 6, l = tid & 63;
    const int wm = w >> 1, wn = w & 1;           // 2x2 waves, each 64x64
    const int lrow = l & 15, lk = (l >> 4) * 8;

    f32x4 acc[4][4] = {};

    for (int k0 = 0; k0 < HIDDEN; k0 += 64) {
        __syncthreads();
        #pragma unroll
        for (int i = 0; i < 4; ++i) {
            int id = tid + i * 256;
            int r = id >> 3, c = id & 7;
            *(half8*)&As[r][c * 8] = *(const half8*)&A[(size_t)(m0 + r) * HIDDEN + k0 + c * 8];
        }
        #pragma unroll
        for (int i = 0; i < 4; ++i) {
            int id = tid + i * 256;
            int r = id >> 3, c = id & 7;
            *(half8*)&Bs[r][c * 8] = *(const half8*)&Bt[(size_t)(n0 + r) * HIDDEN + k0 + c * 8];
        }
        __syncthreads();
        #pragma unroll
        for (int kk = 0; kk < 64; kk += 32) {
            half8 af[4], bf[4];
            #pragma unroll
            for (int m = 0; m < 4; ++m)
                af[m] = *(const half8*)&As[wm * 64 + m * 16 + lrow][kk + lk];
            #pragma unroll
            for (int n = 0; n < 4; ++n)
                bf[n] = *(const half8*)&Bs[wn * 64 + n * 16 + lrow][kk + lk];
            #pragma unroll
            for (int m = 0; m < 4; ++m)
                #pragma unroll
                for (int n = 0; n < 4; ++n)
                    acc[m][n] = __builtin_amdgcn_mfma_f32_16x16x32_f16(af[m], bf[n], acc[m][n], 0, 0, 0);
        }
    }
    // epilogue: + bias, cast fp16
    const int lr4 = (l >> 4) * 4, lc = l & 15;
    #pragma unroll
    for (int n = 0; n < 4; ++n) {
        int gcol = n0 + wn * 64 + n * 16 + lc;
        float b = bias[gcol];
        #pragma unroll
        for (int m = 0; m < 4; ++m) {
            #pragma unroll
            for (int r = 0; r < 4; ++r) {
                int grow = m0 + wm * 64 + m * 16 + lr4 + r;
                Q[(size_t)grow * HIDDEN + gcol] = (_Float16)(acc[m][n][r] + b);
            }
        }
    }
}

// ---------------- fused scores + softmax ----------------
// One workgroup = one (b, h, 64-row q-block). K == Q (shared projection).
// Pass A: accumulate per-row sum(exp(e/8)) (no max subtraction: max e/8 ~ 17, fp32-safe).
// Pass B: recompute tiles, write exp(e/8) * rinv.
__global__ __launch_bounds__(256) void scores_softmax(const _Float16* __restrict__ Qh,
                                                      float* __restrict__ out) {
    __shared__ _Float16 Qs[64][72];
    __shared__ _Float16 Ks[64][72];
    const int qb = blockIdx.x;       // 0..31
    const int h  = blockIdx.y;       // 0..15
    const int b  = blockIdx.z;       // 0..1
    const int tid = threadIdx.x;
    const int w = tid >> 6, l = tid & 63;
    const int hoff = h * 64;
    const _Float16* qbase = Qh + (size_t)b * SEQ * HIDDEN;

    // stage Q tile (once)
    #pragma unroll
    for (int i = 0; i < 2; ++i) {
        int id = tid + i * 256;
        int r = id >> 3, c = id & 7;
        *(half8*)&Qs[r][c * 8] = *(const half8*)&qbase[(size_t)(qb * 64 + r) * HIDDEN + hoff + c * 8];
    }
    __syncthreads();

    const int lrow = l & 15, lk = (l >> 4) * 8;
    half8 aq0 = *(const half8*)&Qs[w * 16 + lrow][lk];
    half8 aq1 = *(const half8*)&Qs[w * 16 + lrow][32 + lk];

    float rsum[4] = {0.f, 0.f, 0.f, 0.f};

    // ---- Pass A: row sums ----
    for (int ks = 0; ks < 32; ++ks) {
        __syncthreads();
        #pragma unroll
        for (int i = 0; i < 2; ++i) {
            int id = tid + i * 256;
            int r = id >> 3, c = id & 7;
            *(half8*)&Ks[r][c * 8] = *(const half8*)&qbase[(size_t)(ks * 64 + r) * HIDDEN + hoff + c * 8];
        }
        __syncthreads();
        f32x4 acc[4] = {};
        #pragma unroll
        for (int n = 0; n < 4; ++n) {
            half8 b0 = *(const half8*)&Ks[n * 16 + lrow][lk];
            half8 b1 = *(const half8*)&Ks[n * 16 + lrow][32 + lk];
            acc[n] = __builtin_amdgcn_mfma_f32_16x16x32_f16(aq0, b0, acc[n], 0, 0, 0);
            acc[n] = __builtin_amdgcn_mfma_f32_16x16x32_f16(aq1, b1, acc[n], 0, 0, 0);
        }
        #pragma unroll
        for (int n = 0; n < 4; ++n)
            #pragma unroll
            for (int r = 0; r < 4; ++r)
                rsum[r] += __expf(acc[n][r] * 0.125f);
    }
    // reduce across the 16 lanes (l&15) of each row group
    #pragma unroll
    for (int d = 1; d < 16; d <<= 1)
        #pragma unroll
        for (int r = 0; r < 4; ++r)
            rsum[r] += __shfl_xor(rsum[r], d, 64);
    float rinv[4];
    #pragma unroll
    for (int r = 0; r < 4; ++r) rinv[r] = 1.0f / rsum[r];

    // ---- Pass B: recompute + write ----
    const size_t outbase = (size_t)(b * 16 + h) * SEQ * SEQ;
    for (int ks = 0; ks < 32; ++ks) {
        __syncthreads();
        #pragma unroll
        for (int i = 0; i < 2; ++i) {
            int id = tid + i * 256;
            int r = id >> 3, c = id & 7;
            *(half8*)&Ks[r][c * 8] = *(const half8*)&qbase[(size_t)(ks * 64 + r) * HIDDEN + hoff + c * 8];
        }
        __syncthreads();
        f32x4 acc[4] = {};
        #pragma unroll
        for (int n = 0; n < 4; ++n) {
            half8 b0 = *(const half8*)&Ks[n * 16 + lrow][lk];
            half8 b1 = *(const half8*)&Ks[n * 16 + lrow][32 + lk];
            acc[n] = __builtin_amdgcn_mfma_f32_16x16x32_f16(aq0, b0, acc[n], 0, 0, 0);
            acc[n] = __builtin_amdgcn_mfma_f32_16x16x32_f16(aq1, b1, acc[n], 0, 0, 0);
        }
        #pragma unroll
        for (int n = 0; n < 4; ++n) {
            int gcol = ks * 64 + n * 16 + (l & 15);
            #pragma unroll
            for (int r = 0; r < 4; ++r) {
                int grow = qb * 64 + w * 16 + (l >> 4) * 4 + r;
                out[outbase + (size_t)grow * SEQ + gcol] = __expf(acc[n][r] * 0.125f) * rinv[r];
            }
        }
    }
}

extern "C" void kernel_launch(void* const* d_in, const int* in_sizes, int n_in,
                              void* d_out, int out_size, void* d_ws, size_t ws_size,
                              hipStream_t stream) {
    const float* x  = (const float*)d_in[0];   // [2,2048,1024]
    const float* Wq = (const float*)d_in[1];   // [1024,1024]
    const float* bq = (const float*)d_in[2];   // [1024]
    float* out = (float*)d_out;                // [2,16,2048,2048]

    _Float16* xh = (_Float16*)d_ws;                    // 8 MB
    _Float16* qh = xh + (size_t)4 * 1024 * 1024;       // 8 MB
    _Float16* wt = qh + (size_t)4 * 1024 * 1024;       // 2 MB

    const int nx = NB * SEQ * HIDDEN;  // 4194304
    cast_x<<<nx / (256 * 4), 256, 0, stream>>>(x, xh, nx);
    cast_wt<<<dim3(32, 32), dim3(32, 8), 0, stream>>>(Wq, wt);
    proj_gemm<<<dim3(NB * SEQ / 128, HIDDEN / 128), 256, 0, stream>>>(xh, wt, bq, qh);
    scores_softmax<<<dim3(SEQ / 64, 16, NB), 256, 0, stream>>>(qh, out);
}